// Round 1
// 112.656 us; speedup vs baseline: 1.0035x; 1.0035x over previous
//
#include <hip/hip_runtime.h>

// SIAF forward. Round 8: eliminate ALL use of the harness workspace d_ws.
// rocprof showed the timed region dominated by __amd_rocclr_fillBufferAligned
// dispatches writing exactly 256 MiB (WRITE_SIZE=262144 KB) at ~42 us each --
// the harness re-poisons d_ws every timed iteration, so staging prep output
// in d_ws costs ~4x our real memory traffic per iteration. The 56 KB prep
// image now lives in a static __device__ buffer (g_ws): siaf_prep writes it,
// siaf_main reads it, both by symbol. Compute kernels otherwise bit-identical
// to round 7 (112 us version).
//
// Round 7 recap: all weights staged once per block into LDS (56 KB image in
// final swizzled layout); GEMM1 = permuted-row MFMA (lane owns the full 8-wide
// hidden vector of layer l=4w+quad); GEMM2 = 16 fp32 FMAs against broadcast
// LDS reads. 1024-thread blocks (16 waves x 16 samples), dynamic LDS 119 KB
// -> 1 block/CU. Rounds 4-6 lesson: compiler won't hold VMEM weight prefetches
// in registers (VGPR stayed 64, spills appeared); LDS staging is the fix.

#define DIMS 64
#define TPB  1024
#define WAVES 16
#define SPW  16

typedef __attribute__((ext_vector_type(8))) short short8;
typedef __attribute__((ext_vector_type(4))) float f32x4;
typedef __attribute__((ext_vector_type(4))) unsigned int uint4v;
typedef unsigned short ushort_t;
typedef unsigned int uint_t;

#if __has_builtin(__builtin_amdgcn_exp2f)
#define YSCALE 2.8853900817779268f      /* 2*log2(e): exp(2y) = exp2(YSCALE*y) */
#define EXPY(x) __builtin_amdgcn_exp2f(x)
#else
#define YSCALE 2.0f
#define EXPY(x) __expf(x)
#endif

// LDS/ws image layout (bytes):
//  A [0,16384):      w1 rows 0..255 (l<32), 64 B/row (k<32 only), 4-chunk XOR swizzle
//  B [16384,49152):  w1 rows 256..511, 128 B/row, 8-chunk XOR swizzle
//  C [49152,53248):  W2 fp32 [64 l][2 o][8 h]
//  D [53248,55296):  b1 fp32 [512] in physical (permuted) row order, YSCALE-scaled
//  E [55296,55808):  b2 fp32 [64][2]
#define A_OFF 0
#define B_OFF 16384
#define C_OFF 49152
#define D_OFF 53248
#define E_OFF 55296
#define WT_BYTES 55808
#define WT_CHUNKS (WT_BYTES / 16)
#define XZ_OFF WT_BYTES
#define LDS_BYTES (WT_BYTES + WAVES * SPW * DIMS * 4)   // 55808 + 65536 = 121344
#define PREP_N (24576 + 1664)

// Static device-side scratch for the prepped weight image. Replaces d_ws so the
// harness's per-iteration 256 MiB workspace re-poison leaves the timed path.
// Written by siaf_prep, read by siaf_main; dispatch-boundary coherence (same
// stream) guarantees visibility, same as the previous d_ws round trip.
__device__ __align__(16) unsigned char g_ws[WT_BYTES];

__device__ __forceinline__ uint_t pk2bf(float a, float b) {
#if __has_builtin(__builtin_amdgcn_cvt_pk_bf16_f32)
    typedef __attribute__((ext_vector_type(2))) __bf16 bf16x2;
    bf16x2 r = __builtin_amdgcn_cvt_pk_bf16_f32(a, b);
    return __builtin_bit_cast(uint_t, r);
#else
    uint_t ua = __float_as_uint(a); ua += 0x7FFFu + ((ua >> 16) & 1u);
    uint_t ub = __float_as_uint(b); ub += 0x7FFFu + ((ub >> 16) & 1u);
    return (ub & 0xFFFF0000u) | (ua >> 16);
#endif
}

__device__ __forceinline__ ushort_t f2bf(float f) {
    uint_t u = __float_as_uint(f);
    u += 0x7FFFu + ((u >> 16) & 1u);
    return (ushort_t)(u >> 16);
}

// logical row L for physical GEMM1 row p (window w=p>>5, tile parity e=(p>>4)&1,
// n=p&15): L = w*32 + (n>>2)*8 + e*4 + (n&3);  l = L>>3, h = L&7.
__device__ __forceinline__ int logrow(int p) {
    int n = p & 15;
    return (p >> 5) * 32 + (n >> 2) * 8 + ((p >> 4) & 1) * 4 + (n & 3);
}

__global__ void siaf_prep(const float* __restrict__ W1, const float* __restrict__ b1,
                          const float* __restrict__ W2, const float* __restrict__ b2) {
    ushort_t* __restrict__ ws_u = (ushort_t*)g_ws;
    int i = blockIdx.x * 256 + threadIdx.x;
    if (i < 8192) {                       // region A: p<256, 32 ushorts/row
        int p = i >> 5, e = i & 31;
        int cp = e >> 3, j = e & 7;
        int k = ((cp ^ (p & 3)) << 3) | j;          // de-swizzled logical k (<32)
        int L = logrow(p), l = L >> 3, h = L & 7;
        float v = (k <= l) ? W1[(l * 8 + h) * 63 + k] * YSCALE : 0.0f;
        ws_u[i] = f2bf(v);
    } else if (i < 24576) {               // region B: p in [256,512), 64 ushorts/row
        int v_ = i - 8192;
        int p = 256 + (v_ >> 6), e = v_ & 63;
        int cp = e >> 3, j = e & 7;
        int k = ((cp ^ (p & 7)) << 3) | j;
        int L = logrow(p), l = L >> 3, h = L & 7;
        float v = (l < 63 && k <= l) ? W1[(l * 8 + h) * 63 + k] * YSCALE : 0.0f;
        ws_u[i] = f2bf(v);
    } else if (i < PREP_N) {              // fp32 regions C/D/E
        int f = i - 24576;
        float* fws = (float*)(ws_u + 24576);
        float v = 0.0f;
        if (f < 1024) {                   // C: W2 [l][o][h]
            int l = f >> 4, o = (f >> 3) & 1, h = f & 7;
            if (l < 63) v = W2[(l * 2 + o) * 8 + h];
        } else if (f < 1536) {            // D: b1 in physical row order
            int p = f - 1024;
            int L = logrow(p), l = L >> 3, h = L & 7;
            if (l < 63) v = b1[l * 8 + h] * YSCALE;
        } else {                          // E: b2 [l][o]
            int j = f - 1536, l = j >> 1, o = j & 1;
            if (l < 63) v = b2[l * 2 + o];
        }
        fws[f] = v;
    }
}

__device__ __forceinline__ float th(float t) {
    // t = YSCALE*y ; tanh(y) = 1 - 2/(exp2(t)+1)
    float e = EXPY(t);
    float r = __builtin_amdgcn_rcpf(e + 1.0f);
    return fmaf(-2.0f, r, 1.0f);
}

__global__ __launch_bounds__(TPB, 4) void siaf_main(
        const float* __restrict__ x, const float* __restrict__ ip,
        float* __restrict__ out, int nB) {
    extern __shared__ unsigned char lds[];

    // ---- stage the 56 KB weight image (already in final layout) ----
    {
        const uint4* __restrict__ wsv = (const uint4*)g_ws;
        uint4* dst = (uint4*)lds;
        for (int c = threadIdx.x; c < WT_CHUNKS; c += TPB) dst[c] = wsv[c];
    }
    __syncthreads();

    const ushort_t* wA  = (const ushort_t*)(lds + A_OFF);
    const ushort_t* wB  = (const ushort_t*)(lds + B_OFF);
    const float*    w2f = (const float*)(lds + C_OFF);
    const float*    b1f = (const float*)(lds + D_OFF);
    const float*    b2f = (const float*)(lds + E_OFF);

    const int tid  = threadIdx.x;
    const int wv   = tid >> 6, lane = tid & 63;
    const int s16  = lane & 15, quad = lane >> 4;
    const int sbase = blockIdx.x * (WAVES * SPW) + wv * SPW;
    float* xzw = (float*)(lds + XZ_OFF) + wv * (SPW * DIMS);

    // ---- stage x: coalesced 1KB/instr, 16B-chunk XOR swizzle (key = row) ----
    #pragma unroll
    for (int g = 0; g < 4; ++g) {
        const float4 v = ((const float4*)(x + (size_t)sbase * DIMS))[g * 64 + lane];
        const int s_loc = 4 * g + quad;
        const int pc = (s16 ^ s_loc) & 15;
        *(float4*)(xzw + s_loc * 64 + pc * 4) = v;
    }
    const float ip0 = ip[0], ip1 = ip[1];

    // ---- B-frag: B[k=quad*8+j][n=s16] from LDS, bf16 ----
    short8 bfr[2];
    #pragma unroll
    for (int kh = 0; kh < 2; ++kh) {
        const int c0 = kh * 8 + quad * 2;
        float4 va = *(const float4*)(xzw + s16 * 64 + ((c0 ^ s16) & 15) * 4);
        float4 vb = *(const float4*)(xzw + s16 * 64 + (((c0 + 1) ^ s16) & 15) * 4);
        uint4v u = {pk2bf(va.x, va.y), pk2bf(va.z, va.w),
                    pk2bf(vb.x, vb.y), pk2bf(vb.z, vb.w)};
        bfr[kh] = __builtin_bit_cast(short8, u);
    }

    float lsum = 0.0f;
    #pragma unroll
    for (int w = 0; w < 16; ++w) {
        // A-frags from LDS (bank-balanced XOR-swizzled rows)
        short8 a00, a10, a01{}, a11{};
        if (w < 8) {
            const ushort_t* base = wA + (w * 32 + s16) * 32;   // 64 B rows
            const int pc = quad ^ (s16 & 3);
            a00 = *(const short8*)(base + pc * 8);
            a10 = *(const short8*)(base + 512 + pc * 8);       // +16 rows
        } else {
            const ushort_t* base = wB + ((w - 8) * 32 + s16) * 64;  // 128 B rows
            const int pc = quad ^ (s16 & 7);
            a00 = *(const short8*)(base + pc * 8);
            a10 = *(const short8*)(base + 1024 + pc * 8);
            a01 = *(const short8*)(base + (pc ^ 4) * 8);
            a11 = *(const short8*)(base + 1024 + (pc ^ 4) * 8);
        }
        const float4 bi0 = *(const float4*)(b1f + w * 32 + quad * 4);       // broadcast
        const float4 bi1 = *(const float4*)(b1f + w * 32 + 16 + quad * 4);  // broadcast

        f32x4 aE = {bi0.x, bi0.y, bi0.z, bi0.w};
        f32x4 aO = {bi1.x, bi1.y, bi1.z, bi1.w};
        aE = __builtin_amdgcn_mfma_f32_16x16x32_bf16(a00, bfr[0], aE, 0, 0, 0);
        aO = __builtin_amdgcn_mfma_f32_16x16x32_bf16(a10, bfr[0], aO, 0, 0, 0);
        if (w >= 8) {
            aE = __builtin_amdgcn_mfma_f32_16x16x32_bf16(a01, bfr[1], aE, 0, 0, 0);
            aO = __builtin_amdgcn_mfma_f32_16x16x32_bf16(a11, bfr[1], aO, 0, 0, 0);
        }

        // lane owns layer l = 4w+quad, sample s16: full hidden vector
        const float t0 = th(aE[0]), t1 = th(aE[1]), t2 = th(aE[2]), t3 = th(aE[3]);
        const float t4 = th(aO[0]), t5 = th(aO[1]), t6 = th(aO[2]), t7 = th(aO[3]);

        const int l = 4 * w + quad;
        const float4 m0 = *(const float4*)(w2f + l * 16);        // broadcast reads
        const float4 m1 = *(const float4*)(w2f + l * 16 + 4);
        const float4 a0 = *(const float4*)(w2f + l * 16 + 8);
        const float4 a1 = *(const float4*)(w2f + l * 16 + 12);
        const float2 bb = *(const float2*)(b2f + l * 2);

        float mu = bb.x;
        mu = fmaf(m0.x, t0, mu); mu = fmaf(m0.y, t1, mu);
        mu = fmaf(m0.z, t2, mu); mu = fmaf(m0.w, t3, mu);
        mu = fmaf(m1.x, t4, mu); mu = fmaf(m1.y, t5, mu);
        mu = fmaf(m1.z, t6, mu); mu = fmaf(m1.w, t7, mu);
        float al = bb.y;
        al = fmaf(a0.x, t0, al); al = fmaf(a0.y, t1, al);
        al = fmaf(a0.z, t2, al); al = fmaf(a0.w, t3, al);
        al = fmaf(a1.x, t4, al); al = fmaf(a1.y, t5, al);
        al = fmaf(a1.z, t6, al); al = fmaf(a1.w, t7, al);

        // epilogue: z[d=l+1] in-place in LDS (l=63 pad lane handles d=0 instead)
        const bool pad = (l == 63);
        const float alB = pad ? ip1 : al;
        const float muB = pad ? ip0 : mu;
        const int d = pad ? 0 : (l + 1);
        float* pz = xzw + s16 * 64 + ((((d >> 2) ^ s16) & 15) << 2) + (d & 3);
        *pz = fmaf(*pz, __expf(alB), muB);
        lsum += alB;
    }

    // ---- coalesced LDS -> global z store ----
    #pragma unroll
    for (int g = 0; g < 4; ++g) {
        const int s_loc = 4 * g + quad;
        const int pc = (s16 ^ s_loc) & 15;
        const float4 v = *(const float4*)(xzw + s_loc * 64 + pc * 4);
        ((float4*)(out + (size_t)sbase * DIMS))[g * 64 + lane] = v;
    }

    // ---- log_det: sum the 4 quad-partials per sample ----
    {
        float v = lsum;
        int r1 = __builtin_amdgcn_ds_swizzle(__float_as_int(v), 0x401F);  // xor 16
        v += __int_as_float(r1);
        int r2 = __builtin_amdgcn_ds_bpermute((lane ^ 32) << 2, __float_as_int(v));
        v += __int_as_float(r2);
        if (quad == 0)
            out[(size_t)nB * DIMS + sbase + s16] = v;
    }
}

extern "C" void kernel_launch(void* const* d_in, const int* in_sizes, int n_in,
                              void* d_out, int out_size, void* d_ws, size_t ws_size,
                              hipStream_t stream) {
    const float* x  = (const float*)d_in[0];
    const float* ip = (const float*)d_in[1];
    const float* W1 = (const float*)d_in[2];
    const float* b1 = (const float*)d_in[3];
    const float* W2 = (const float*)d_in[4];
    const float* b2 = (const float*)d_in[5];
    float* out = (float*)d_out;
    (void)d_ws; (void)ws_size;              // workspace deliberately unused (see header)

    const int nB = in_sizes[0] / DIMS;      // 131072

    (void)hipFuncSetAttribute((const void*)siaf_main,
                              hipFuncAttributeMaxDynamicSharedMemorySize, LDS_BYTES);

    siaf_prep<<<(PREP_N + 255) / 256, 256, 0, stream>>>(W1, b1, W2, b2);
    siaf_main<<<nB / (WAVES * SPW), TPB, LDS_BYTES, stream>>>(x, ip, out, nB);
}